// Round 6
// baseline (265.287 us; speedup 1.0000x reference)
//
// round 5: 32 rows/wave + batched gather prefetch (4 k-offsets, 8 gathers in flight)
#include <hip/hip_runtime.h>
#include <hip/hip_bf16.h>

#define NV 300000
#define CH 32
#define KK 27
#define KP 28            // padded k-slices (slice 27 = zeros)

typedef __attribute__((ext_vector_type(8))) short bf16x8;
typedef __attribute__((ext_vector_type(4))) float f32x4;

// ws layout (bytes)
#define XB_OFF   0u
#define HB_OFF   19200128u            // (NV+1)*CH*2 = 19200064, padded
#define W0T_OFF  38400256u            // KP*CH*CH*2 = 57344
#define W1T_OFF  38457600u
// end ~38.5 MB

__device__ __forceinline__ unsigned short f2b(float f) {
    unsigned int u = __builtin_bit_cast(unsigned int, f);
    unsigned int r = (u + 0x7FFFu + ((u >> 16) & 1u)) >> 16;
    return (unsigned short)r;
}

// --- prep: x -> bf16 (+pad row), zero h pad row, transpose weights to [k][d][c] bf16 (28 slices)
__global__ __launch_bounds__(256) void prep_kernel(
    const float* __restrict__ x,
    const float* __restrict__ w0,
    const float* __restrict__ w1,
    unsigned short* __restrict__ xb,
    unsigned short* __restrict__ hb,
    unsigned short* __restrict__ w0t,
    unsigned short* __restrict__ w1t)
{
    const int NX = NV * CH / 8;  // 1,200,000
    int tid = blockIdx.x * blockDim.x + threadIdx.x;
    if (tid < NX) {
        int base = tid * 8;
        const float4* p = reinterpret_cast<const float4*>(x + base);
        float4 a = p[0], b = p[1];
        union { unsigned short u[8]; bf16x8 v; } pk;
        pk.u[0] = f2b(a.x); pk.u[1] = f2b(a.y); pk.u[2] = f2b(a.z); pk.u[3] = f2b(a.w);
        pk.u[4] = f2b(b.x); pk.u[5] = f2b(b.y); pk.u[6] = f2b(b.z); pk.u[7] = f2b(b.w);
        *reinterpret_cast<bf16x8*>(xb + base) = pk.v;
        return;
    }
    int t = tid - NX;
    if (t < 4) {  // zero xb pad row
        union { unsigned short u[8]; bf16x8 v; } z;
        for (int j = 0; j < 8; ++j) z.u[j] = 0;
        *reinterpret_cast<bf16x8*>(xb + NV * CH + t * 8) = z.v;
        return;
    }
    t -= 4;
    if (t < 4) {  // zero hb pad row
        union { unsigned short u[8]; bf16x8 v; } z;
        for (int j = 0; j < 8; ++j) z.u[j] = 0;
        *reinterpret_cast<bf16x8*>(hb + NV * CH + t * 8) = z.v;
        return;
    }
    t -= 4;
    const int WELEM = KP * CH * CH;  // 28672
    if (t < 2 * WELEM) {  // wt[k][d][c] = w[k][c][d]; k==27 -> 0
        int which = t >= WELEM;
        int e = t - which * WELEM;
        int k = e >> 10;
        int rem = e & 1023;
        int d = rem >> 5;
        int c = rem & 31;
        unsigned short* o = which ? w1t : w0t;
        if (k == KK) {
            o[e] = 0;
        } else {
            const float* w = which ? w1 : w0;
            o[e] = f2b(w[k * 1024 + c * 32 + d]);
        }
    }
}

// --- conv layer: 32 output rows per wave (2 tiles), batched k-loop, mfma 16x16x32 bf16
template <bool FIRST>
__global__ __launch_bounds__(256) void conv_kernel(
    const unsigned short* __restrict__ in_b,  // (NV+1)*CH bf16
    const int* __restrict__ nbr,              // KK*NV
    const unsigned short* __restrict__ wt,    // KP*CH*CH bf16, [k][d][c], slice 27 = 0
    const float* __restrict__ bias,           // CH
    const float* __restrict__ xres,           // NV*CH f32 (layer2) or null
    unsigned short* __restrict__ out_b,       // layer1 out (bf16)
    float* __restrict__ out_f)                // layer2 out (f32)
{
    const int wave = (blockIdx.x * blockDim.x + threadIdx.x) >> 6;
    if (wave >= NV / 32) return;   // 9375 waves, exact
    const int lane = threadIdx.x & 63;
    const int r = lane & 15;
    const int g = lane >> 4;
    const int row0 = wave * 32;
    const int i0 = row0 + r;
    const int i1 = row0 + 16 + r;

    f32x4 acc00 = {0.f, 0.f, 0.f, 0.f};
    f32x4 acc01 = {0.f, 0.f, 0.f, 0.f};
    f32x4 acc10 = {0.f, 0.f, 0.f, 0.f};
    f32x4 acc11 = {0.f, 0.f, 0.f, 0.f};

    const unsigned short* wt_r0 = wt + r * CH + g * 8;
    const unsigned short* wt_r1 = wt + (r + 16) * CH + g * 8;

#pragma unroll
    for (int kb = 0; kb < KP; kb += 4) {
        int idx0[4], idx1[4];
#pragma unroll
        for (int j = 0; j < 4; ++j) {
            int kk = kb + j;
            int ks = kk < KK ? kk : KK - 1;   // k=27 reuses 26 (B slice is zero)
            idx0[j] = nbr[ks * NV + i0];
            idx1[j] = nbr[ks * NV + i1];
        }
        bf16x8 a0[4], a1[4];
#pragma unroll
        for (int j = 0; j < 4; ++j) {
            a0[j] = *reinterpret_cast<const bf16x8*>(in_b + idx0[j] * CH + g * 8);
            a1[j] = *reinterpret_cast<const bf16x8*>(in_b + idx1[j] * CH + g * 8);
        }
#pragma unroll
        for (int j = 0; j < 4; ++j) {
            int kk = kb + j;
            bf16x8 b0 = *reinterpret_cast<const bf16x8*>(wt_r0 + kk * 1024);
            bf16x8 b1 = *reinterpret_cast<const bf16x8*>(wt_r1 + kk * 1024);
            acc00 = __builtin_amdgcn_mfma_f32_16x16x32_bf16(a0[j], b0, acc00, 0, 0, 0);
            acc10 = __builtin_amdgcn_mfma_f32_16x16x32_bf16(a1[j], b0, acc10, 0, 0, 0);
            acc01 = __builtin_amdgcn_mfma_f32_16x16x32_bf16(a0[j], b1, acc01, 0, 0, 0);
            acc11 = __builtin_amdgcn_mfma_f32_16x16x32_bf16(a1[j], b1, acc11, 0, 0, 0);
        }
    }

    const float bs0 = bias[r];
    const float bs1 = bias[r + 16];
#pragma unroll
    for (int j = 0; j < 4; ++j) {
        int ra = row0 + g * 4 + j;        // tile0 row
        int rb = ra + 16;                 // tile1 row
        float v00 = acc00[j] + bs0;       // (ra, r)
        float v01 = acc01[j] + bs1;       // (ra, r+16)
        float v10 = acc10[j] + bs0;       // (rb, r)
        float v11 = acc11[j] + bs1;       // (rb, r+16)
        if (FIRST) {
            out_b[ra * CH + r]      = f2b(fmaxf(v00, 0.f));
            out_b[ra * CH + r + 16] = f2b(fmaxf(v01, 0.f));
            out_b[rb * CH + r]      = f2b(fmaxf(v10, 0.f));
            out_b[rb * CH + r + 16] = f2b(fmaxf(v11, 0.f));
        } else {
            out_f[ra * CH + r]      = v00 + xres[ra * CH + r];
            out_f[ra * CH + r + 16] = v01 + xres[ra * CH + r + 16];
            out_f[rb * CH + r]      = v10 + xres[rb * CH + r];
            out_f[rb * CH + r + 16] = v11 + xres[rb * CH + r + 16];
        }
    }
}

extern "C" void kernel_launch(void* const* d_in, const int* in_sizes, int n_in,
                              void* d_out, int out_size, void* d_ws, size_t ws_size,
                              hipStream_t stream) {
    const float* x   = (const float*)d_in[0];
    const int* nbr   = (const int*)d_in[1];
    const float* w0  = (const float*)d_in[2];
    const float* b0  = (const float*)d_in[3];
    const float* w1  = (const float*)d_in[4];
    const float* b1  = (const float*)d_in[5];
    float* out = (float*)d_out;

    char* ws = (char*)d_ws;
    unsigned short* xb  = (unsigned short*)(ws + XB_OFF);
    unsigned short* hb  = (unsigned short*)(ws + HB_OFF);
    unsigned short* w0t = (unsigned short*)(ws + W0T_OFF);
    unsigned short* w1t = (unsigned short*)(ws + W1T_OFF);

    // prep
    {
        int total = NV * CH / 8 + 8 + 2 * KP * CH * CH;  // 1,257,352
        int blocks = (total + 255) / 256;
        prep_kernel<<<blocks, 256, 0, stream>>>(x, w0, w1, xb, hb, w0t, w1t);
    }
    // conv layers: one wave per 32 rows
    int threads = (NV / 32) * 64;        // 600,000
    int blocks = (threads + 255) / 256;  // 2344
    conv_kernel<true><<<blocks, 256, 0, stream>>>(xb, nbr, w0t, b0, nullptr, hb, nullptr);
    conv_kernel<false><<<blocks, 256, 0, stream>>>(hb, nbr, w1t, b1, x, nullptr, out);
}